// Round 10
// baseline (62.853 us; speedup 1.0000x reference)
//
#include <hip/hip_runtime.h>
#include <hip/hip_cooperative_groups.h>
#include <math.h>

namespace cg = cooperative_groups;

#define NROWS 2048
#define DDIM 32

// ---------------------------------------------------------------------------
// Single cooperative kernel. 256 blocks (1/CU) x 512 threads (2 waves/SIMD).
// Phase 0: block b computes stats partials over rows [8b, 8b+8) of x AND y
//          (512 loads/block), reduced via shfl+LDS -> part[b][128].
// grid.sync()
// Phase 1: finalize mean / 1/(std+eps) (ddof=1) from 256 partials (8 lanes
//          per (array,col), 32 partials each, shfl-reduce).
// Phase 2: stage 128x128 tile data into XOR-swizzled LDS slots:
//   sD[side][s*128 + (idx ^ (s&7))], s=0..15: (hc0,hs0,hc1,hs1) d-pair slots,
//   s=16..23: xn quads. x side folds ALPHA=0.5 into hc/hs.
// Phase 3: r7 compute core: 24 phases, 12 ds_read_b128 each, 8x4 micro-tile.
// classical = exp(2*dot - nx - ny); quantum term = 0.5 + hcx*cy + hsx*sy.
// ---------------------------------------------------------------------------
__global__ __launch_bounds__(512, 2) void HybridKernel_coop(
    const float* __restrict__ x, const float* __restrict__ y,
    float* __restrict__ part, float* __restrict__ out) {
  __shared__ float4 sD[2][24 * 128];
  __shared__ float sNrm[2][128];
  __shared__ float sMu[2][32];
  __shared__ float sInv[2][32];
  __shared__ float2 sP[8][32];

  const int t = threadIdx.x;
  const int bx = blockIdx.x, by = blockIdx.y;
  const int b = by * 16 + bx;
  const int i0 = by * 128;
  const int j0 = bx * 128;

  // --- hoist tile global loads (independent of stats) ---
  float4 gx[2], gy[2];
#pragma unroll
  for (int rep = 0; rep < 2; ++rep) {
    const int u = t + 512 * rep;
    const int row = u >> 3;
    const int q = u & 7;
    gx[rep] = *reinterpret_cast<const float4*>(&x[(i0 + row) * DDIM + q * 4]);
    gy[rep] = *reinterpret_cast<const float4*>(&y[(j0 + row) * DDIM + q * 4]);
  }

  // --- Phase 0: block-local stats partials over rows [8b, 8b+8) ---
  {
    const int a = t >> 8;         // 0=x, 1=y
    const int c = t & 31;         // column
    const float* in = a ? y : x;  // row = 8b + ((t>>5)&7)
    const float v = in[(b * 8 + ((t >> 5) & 7)) * DDIM + c];
    float s = v, s2 = v * v;
    s += __shfl_xor(s, 32);   // combine row pair within wave
    s2 += __shfl_xor(s2, 32);
    const int w = t >> 6;  // 0..7 (waves 0-3: x, 4-7: y)
    if ((t & 63) < 32) sP[w][c] = make_float2(s, s2);
  }
  __syncthreads();
  if (t < 64) {
    const int a = t >> 5;
    const int c = t & 31;
    float S = 0.f, Q = 0.f;
#pragma unroll
    for (int w = 0; w < 4; ++w) {
      S += sP[a * 4 + w][c].x;
      Q += sP[a * 4 + w][c].y;
    }
    part[b * 128 + a * 32 + c] = S;
    part[b * 128 + 64 + a * 32 + c] = Q;
  }

  cg::this_grid().sync();

  // --- Phase 1: finalize stats from 256 block partials ---
  {
    const int a = t >> 8;
    const int c = (t >> 3) & 31;
    const int g = t & 7;
    float S = 0.f, Q = 0.f;
#pragma unroll 8
    for (int m = 0; m < 32; ++m) {
      const int bb = g + 8 * m;
      S += part[bb * 128 + a * 32 + c];
      Q += part[bb * 128 + 64 + a * 32 + c];
    }
    S += __shfl_xor(S, 1);
    S += __shfl_xor(S, 2);
    S += __shfl_xor(S, 4);
    Q += __shfl_xor(Q, 1);
    Q += __shfl_xor(Q, 2);
    Q += __shfl_xor(Q, 4);
    if (g == 0) {
      const float n = (float)NROWS;
      const float mean = S / n;
      const float var = fmaxf((Q - S * mean) / (n - 1.f), 0.f);
      sMu[a][c] = mean;
      sInv[a][c] = 1.f / (sqrtf(var) + 1e-8f);
    }
  }
  __syncthreads();

  // --- Phase 2: staging (identical to r7) ---
#pragma unroll
  for (int rep = 0; rep < 2; ++rep) {
    const int u = t + 512 * rep;
    const int row = u >> 3;
    const int q = u & 7;
#pragma unroll
    for (int side = 0; side < 2; ++side) {
      const float4 g = side ? gy[rep] : gx[rep];
      const float sc = side ? 1.0f : 0.5f;
      const float gv[4] = {g.x, g.y, g.z, g.w};
      float xn[4], hc[4], hs[4];
      float nrm = 0.f;
#pragma unroll
      for (int k = 0; k < 4; ++k) {
        const int d = q * 4 + k;
        xn[k] = (gv[k] - sMu[side][d]) * sInv[side][d];
        nrm = fmaf(xn[k], xn[k], nrm);
        float sn, cs;
        __sincosf(gv[k], &sn, &cs);
        hc[k] = sc * cs;
        hs[k] = sc * sn;
      }
      sD[side][(16 + q) * 128 + (row ^ q)] =
          make_float4(xn[0], xn[1], xn[2], xn[3]);
      const int dp0 = 2 * q, dp1 = 2 * q + 1;
      sD[side][dp0 * 128 + (row ^ (dp0 & 7))] =
          make_float4(hc[0], hs[0], hc[1], hs[1]);
      sD[side][dp1 * 128 + (row ^ (dp1 & 7))] =
          make_float4(hc[2], hs[2], hc[3], hs[3]);
      nrm += __shfl_xor(nrm, 1);
      nrm += __shfl_xor(nrm, 2);
      nrm += __shfl_xor(nrm, 4);
      if ((t & 7) == 0) sNrm[side][row] = nrm;
    }
  }
  __syncthreads();

  // --- Phase 3: r7 compute core: 24 phases, 8x4 outputs per thread ---
  const int tx = t & 31;
  const int ty = t >> 5;
  const float4* sD0 = &sD[0][0];
  const float4* sD1 = &sD[1][0];

  float acc[8][4];
  float qp[8][4];
#pragma unroll
  for (int r = 0; r < 8; ++r)
#pragma unroll
    for (int c = 0; c < 4; ++c) {
      acc[r][c] = 0.f;
      qp[r][c] = 1.f;
    }

#pragma unroll
  for (int q = 0; q < 8; ++q) {
    // phase C: xn quad (slot 16+q)
    {
      const int S = 16 + q;
      const int sw = S & 7;
      float4 FX[8], FY[4];
#pragma unroll
      for (int i = 0; i < 8; ++i) FX[i] = sD0[S * 128 + ((ty + 16 * i) ^ sw)];
#pragma unroll
      for (int j = 0; j < 4; ++j) FY[j] = sD1[S * 128 + ((tx + 32 * j) ^ sw)];
#pragma unroll
      for (int r = 0; r < 8; ++r)
#pragma unroll
        for (int c = 0; c < 4; ++c) {
          float a = acc[r][c];
          a = fmaf(FX[r].x, FY[c].x, a);
          a = fmaf(FX[r].y, FY[c].y, a);
          a = fmaf(FX[r].z, FY[c].z, a);
          a = fmaf(FX[r].w, FY[c].w, a);
          acc[r][c] = a;
        }
    }
    // phases Q0, Q1: cos/sin pairs (slots 2q, 2q+1)
#pragma unroll
    for (int h = 0; h < 2; ++h) {
      const int S = 2 * q + h;
      const int sw = S & 7;
      float4 FX[8], FY[4];
#pragma unroll
      for (int i = 0; i < 8; ++i) FX[i] = sD0[S * 128 + ((ty + 16 * i) ^ sw)];
#pragma unroll
      for (int j = 0; j < 4; ++j) FY[j] = sD1[S * 128 + ((tx + 32 * j) ^ sw)];
#pragma unroll
      for (int r = 0; r < 8; ++r)
#pragma unroll
        for (int c = 0; c < 4; ++c) {
          const float t0 =
              fmaf(FX[r].x, FY[c].x, fmaf(FX[r].y, FY[c].y, 0.5f));
          const float t1 =
              fmaf(FX[r].z, FY[c].z, fmaf(FX[r].w, FY[c].w, 0.5f));
          qp[r][c] *= t0 * t1;
        }
    }
  }

  // --- epilogue ---
  float nx[8], ny[4];
#pragma unroll
  for (int r = 0; r < 8; ++r) nx[r] = sNrm[0][ty + 16 * r];
#pragma unroll
  for (int c = 0; c < 4; ++c) ny[c] = sNrm[1][tx + 32 * c];

#pragma unroll
  for (int r = 0; r < 8; ++r) {
    const int row = i0 + ty + 16 * r;
    float* o = out + (size_t)row * NROWS + j0;
#pragma unroll
    for (int c = 0; c < 4; ++c) {
      const float cl = __expf(2.f * acc[r][c] - nx[r] - ny[c]);
      o[tx + 32 * c] = 0.5f * (cl + qp[r][c]);
    }
  }
}

extern "C" void kernel_launch(void* const* d_in, const int* in_sizes, int n_in,
                              void* d_out, int out_size, void* d_ws,
                              size_t ws_size, hipStream_t stream) {
  const float* x = (const float*)d_in[0];
  const float* y = (const float*)d_in[1];
  float* part = (float*)d_ws;  // 256*128 floats = 128 KB
  float* out = (float*)d_out;

  void* args[] = {(void*)&x, (void*)&y, (void*)&part, (void*)&out};
  hipLaunchCooperativeKernel((const void*)HybridKernel_coop, dim3(16, 16),
                             dim3(512), args, 0, stream);
}

// Round 11
// 26.416 us; speedup vs baseline: 2.3793x; 2.3793x over previous
//
#include <hip/hip_runtime.h>
#include <math.h>

#define NROWS 2048
#define DDIM 32
#define SBLK 16               // stats blocks per array
#define SROWS (NROWS / SBLK)  // 128 rows per stats block

// ---------------------------------------------------------------------------
// Stage 1: coalesced per-column partial sums (identical to r7 champion).
// ---------------------------------------------------------------------------
__global__ __launch_bounds__(256) void HybridKernel_stats_partial(
    const float* __restrict__ x, const float* __restrict__ y,
    float* __restrict__ part) {
  const int b = blockIdx.x;
  const int a = b >> 4;
  const int blk = b & (SBLK - 1);
  const float* in = a ? y : x;
  const int t = threadIdx.x;
  const int col = t & 31;
  const int rg = t >> 5;  // 0..7
  float s = 0.f, s2 = 0.f;
  const int r0 = blk * SROWS + rg;
#pragma unroll
  for (int i = 0; i < SROWS / 8; ++i) {
    float v = in[(r0 + i * 8) * DDIM + col];
    s += v;
    s2 = fmaf(v, v, s2);
  }
  __shared__ float ss[8][32];
  __shared__ float sq[8][32];
  ss[rg][col] = s;
  sq[rg][col] = s2;
  __syncthreads();
  if (t < 32) {
    float S = 0.f, Q = 0.f;
#pragma unroll
    for (int g = 0; g < 8; ++g) {
      S += ss[g][t];
      Q += sq[g][t];
    }
    part[b * 64 + t] = S;
    part[b * 64 + 32 + t] = Q;
  }
}

// slot schedule: per quad q: C(xn slot 16+q), Q(cs slot 2q), Q(cs slot 2q+1)
constexpr int SLOT(int p) {
  const int q = p / 3, k = p % 3;
  return k == 0 ? 16 + q : 2 * q + k - 1;
}

// ---------------------------------------------------------------------------
// Stage 2: 128x128 tile per 512-thread block (2 waves/SIMD). Micro-tile 8x4.
// LDS slot array sD[side][s*128 + (idx ^ (s&7))], 24 slots per side:
//   s = 0..15 : cos/sin d-pair dp=s -> float4 (hc0,hs0,hc1,hs1), d = 2s,2s+1
//   s = 16..23: xn quad q=s-16     -> float4 xn[4q..4q+3]
// x side folds ALPHA: hc=0.5cos(x), hs=0.5sin(x); y side plain cos/sin.
// Core: fully-unrolled 24-phase depth-1 software pipeline (A/B fragment
// double-buffer, ~190 VGPR demand) + s_setprio around FMA nests (T5).
// classical = exp(2*dot - nx - ny); quantum term = 0.5 + hcx*cy + hsx*sy.
// ---------------------------------------------------------------------------
__global__ __launch_bounds__(512, 2) void HybridKernel_main(
    const float* __restrict__ x, const float* __restrict__ y,
    const float* __restrict__ part, float* __restrict__ out) {
  __shared__ float4 sD[2][24 * 128];
  __shared__ float sNrm[2][128];
  __shared__ float sMu[2][32];
  __shared__ float sInv[2][32];

  const int t = threadIdx.x;
  const int i0 = blockIdx.y * 128;
  const int j0 = blockIdx.x * 128;

  // --- hoist tile global loads (independent of stats) ---
  float4 gx[2], gy[2];
#pragma unroll
  for (int rep = 0; rep < 2; ++rep) {
    const int u = t + 512 * rep;
    const int row = u >> 3;
    const int q = u & 7;
    gx[rep] = *reinterpret_cast<const float4*>(&x[(i0 + row) * DDIM + q * 4]);
    gy[rep] = *reinterpret_cast<const float4*>(&y[(j0 + row) * DDIM + q * 4]);
  }

  // --- finalize stats (mean, 1/(std+eps), ddof=1) from partials ---
  if (t < 64) {
    const int a = t >> 5;
    const int c = t & 31;
    float S = 0.f, Q = 0.f;
#pragma unroll
    for (int bb = 0; bb < SBLK; ++bb) {
      S += part[(a * SBLK + bb) * 64 + c];
      Q += part[(a * SBLK + bb) * 64 + 32 + c];
    }
    const float n = (float)NROWS;
    const float mean = S / n;
    const float var = fmaxf((Q - S * mean) / (n - 1.f), 0.f);
    sMu[a][c] = mean;
    sInv[a][c] = 1.f / (sqrtf(var) + 1e-8f);
  }
  __syncthreads();

  // --- staging: 1024 (row,quad) units per side, 2 reps over 512 threads ---
#pragma unroll
  for (int rep = 0; rep < 2; ++rep) {
    const int u = t + 512 * rep;
    const int row = u >> 3;
    const int q = u & 7;
#pragma unroll
    for (int side = 0; side < 2; ++side) {
      const float4 g = side ? gy[rep] : gx[rep];
      const float sc = side ? 1.0f : 0.5f;
      const float gv[4] = {g.x, g.y, g.z, g.w};
      float xn[4], hc[4], hs[4];
      float nrm = 0.f;
#pragma unroll
      for (int k = 0; k < 4; ++k) {
        const int d = q * 4 + k;
        xn[k] = (gv[k] - sMu[side][d]) * sInv[side][d];
        nrm = fmaf(xn[k], xn[k], nrm);
        float sn, cs;
        __sincosf(gv[k], &sn, &cs);
        hc[k] = sc * cs;
        hs[k] = sc * sn;
      }
      sD[side][(16 + q) * 128 + (row ^ q)] =
          make_float4(xn[0], xn[1], xn[2], xn[3]);
      const int dp0 = 2 * q, dp1 = 2 * q + 1;
      sD[side][dp0 * 128 + (row ^ (dp0 & 7))] =
          make_float4(hc[0], hs[0], hc[1], hs[1]);
      sD[side][dp1 * 128 + (row ^ (dp1 & 7))] =
          make_float4(hc[2], hs[2], hc[3], hs[3]);
      nrm += __shfl_xor(nrm, 1);
      nrm += __shfl_xor(nrm, 2);
      nrm += __shfl_xor(nrm, 4);
      if ((t & 7) == 0) sNrm[side][row] = nrm;
    }
  }
  __syncthreads();

  // --- main compute: fully-unrolled 24-phase pipeline, 8x4 per thread ---
  const int tx = t & 31;
  const int ty = t >> 5;
  const float4* sD0 = &sD[0][0];
  const float4* sD1 = &sD[1][0];

  float acc[8][4];
  float qp[8][4];
#pragma unroll
  for (int r = 0; r < 8; ++r)
#pragma unroll
    for (int c = 0; c < 4; ++c) {
      acc[r][c] = 0.f;
      qp[r][c] = 1.f;
    }

  float4 AX[8], AY[4], BX[8], BY[4];

#define LOADP(S_, FX_, FY_)                                          \
  {                                                                  \
    constexpr int s_ = (S_);                                         \
    constexpr int sw_ = s_ & 7;                                      \
    _Pragma("unroll") for (int i = 0; i < 8; ++i) FX_[i] =           \
        sD0[s_ * 128 + ((ty + 16 * i) ^ sw_)];                       \
    _Pragma("unroll") for (int j = 0; j < 4; ++j) FY_[j] =           \
        sD1[s_ * 128 + ((tx + 32 * j) ^ sw_)];                       \
  }

#define COMPP(S_, FX_, FY_)                                                \
  {                                                                        \
    __builtin_amdgcn_s_setprio(1);                                         \
    if constexpr ((S_) >= 16) {                                            \
      _Pragma("unroll") for (int r = 0; r < 8; ++r)                        \
          _Pragma("unroll") for (int c = 0; c < 4; ++c) {                  \
        float a = acc[r][c];                                               \
        a = fmaf(FX_[r].x, FY_[c].x, a);                                   \
        a = fmaf(FX_[r].y, FY_[c].y, a);                                   \
        a = fmaf(FX_[r].z, FY_[c].z, a);                                   \
        a = fmaf(FX_[r].w, FY_[c].w, a);                                   \
        acc[r][c] = a;                                                     \
      }                                                                    \
    } else {                                                               \
      _Pragma("unroll") for (int r = 0; r < 8; ++r)                        \
          _Pragma("unroll") for (int c = 0; c < 4; ++c) {                  \
        const float t0 =                                                   \
            fmaf(FX_[r].x, FY_[c].x, fmaf(FX_[r].y, FY_[c].y, 0.5f));      \
        const float t1 =                                                   \
            fmaf(FX_[r].z, FY_[c].z, fmaf(FX_[r].w, FY_[c].w, 0.5f));      \
        qp[r][c] *= t0 * t1;                                               \
      }                                                                    \
    }                                                                      \
    __builtin_amdgcn_s_setprio(0);                                         \
  }

  // prologue
  LOADP(SLOT(0), AX, AY);

#define STEP2(P_)                                   \
  {                                                 \
    LOADP(SLOT((P_) + 1), BX, BY);                  \
    COMPP(SLOT(P_), AX, AY);                        \
    if constexpr ((P_) + 2 < 24) {                  \
      LOADP(SLOT((P_) + 2), AX, AY);                \
    }                                               \
    COMPP(SLOT((P_) + 1), BX, BY);                  \
  }

  STEP2(0) STEP2(2) STEP2(4) STEP2(6) STEP2(8) STEP2(10)
  STEP2(12) STEP2(14) STEP2(16) STEP2(18) STEP2(20) STEP2(22)

#undef STEP2
#undef COMPP
#undef LOADP

  // --- epilogue ---
  float nx[8], ny[4];
#pragma unroll
  for (int r = 0; r < 8; ++r) nx[r] = sNrm[0][ty + 16 * r];
#pragma unroll
  for (int c = 0; c < 4; ++c) ny[c] = sNrm[1][tx + 32 * c];

#pragma unroll
  for (int r = 0; r < 8; ++r) {
    const int row = i0 + ty + 16 * r;
    float* o = out + (size_t)row * NROWS + j0;
#pragma unroll
    for (int c = 0; c < 4; ++c) {
      const float cl = __expf(2.f * acc[r][c] - nx[r] - ny[c]);
      o[tx + 32 * c] = 0.5f * (cl + qp[r][c]);
    }
  }
}

extern "C" void kernel_launch(void* const* d_in, const int* in_sizes, int n_in,
                              void* d_out, int out_size, void* d_ws,
                              size_t ws_size, hipStream_t stream) {
  const float* x = (const float*)d_in[0];
  const float* y = (const float*)d_in[1];
  float* part = (float*)d_ws;  // 2*SBLK*64 = 2048 floats
  float* out = (float*)d_out;

  HybridKernel_stats_partial<<<2 * SBLK, 256, 0, stream>>>(x, y, part);
  dim3 grid(NROWS / 128, NROWS / 128);
  HybridKernel_main<<<grid, 512, 0, stream>>>(x, y, part, out);
}